// Round 10
// baseline (181.380 us; speedup 1.0000x reference)
//
#include <hip/hip_runtime.h>
#include <hip/hip_bf16.h>
#include <math.h>

#define NB 64
#define LD 512
#define LP 1024
#define DD 128
#define KK 64

using half8 = __attribute__((ext_vector_type(8))) _Float16;
using half4 = __attribute__((ext_vector_type(4))) _Float16;
using f32x4 = __attribute__((ext_vector_type(4))) float;

// fast tanh: 1 - 2/(e^{2x}+1); inf-safe both tails
__device__ __forceinline__ float ftanh(float x) {
    float e = __expf(2.0f * x);
    return 1.0f - 2.0f / (e + 1.0f);
}

// ---------------- conversion kernels ----------------
__global__ void k_conv(const float* __restrict__ in, _Float16* __restrict__ out, int n) {
    int i = (blockIdx.x * blockDim.x + threadIdx.x) * 4;
    int stride = gridDim.x * blockDim.x * 4;
    for (; i < n; i += stride) {
        float4 v = *reinterpret_cast<const float4*>(in + i);
        half4 h;
        h.x = (_Float16)v.x; h.y = (_Float16)v.y; h.z = (_Float16)v.z; h.w = (_Float16)v.w;
        *reinterpret_cast<half4*>(out + i) = h;
    }
}

__global__ void k_wbt(const float* __restrict__ Wb, _Float16* __restrict__ WbT) {
    int t = blockIdx.x * 256 + threadIdx.x;
    int d = t >> 7, e = t & 127;
    WbT[t] = (_Float16)Wb[e * 128 + d];
}

__global__ void k_sentinel(float* out) {
    if (threadIdx.x == 0 && blockIdx.x == 0) out[0] = 1000.0f;
}

// ---------------- plain batched NT GEMM, fp16 in/out (tb, Wxd, Wpt) ----------------
__global__ __launch_bounds__(256)
void k_gemm(const _Float16* __restrict__ A, long sA,
            const _Float16* __restrict__ Bm, long sB,
            _Float16* __restrict__ Out, long sOut,
            int N, int Kd, int tilesM, int tilesN)
{
    __shared__ alignas(16) _Float16 smem[64 * 72 + 128 * 72];
    _Float16* As = smem;
    _Float16* Bs = smem + 64 * 72;

    int bid = blockIdx.x;
    int tpb = tilesM * tilesN;
    int b = bid / tpb;
    int t = bid % tpb;
    int m0 = (t / tilesN) * 64;
    int n0 = (t % tilesN) * 128;

    const _Float16* Ab = A + (long)b * sA;
    const _Float16* Bb = Bm + (long)b * sB;

    int tid = threadIdx.x;
    int lane = tid & 63;
    int wid = tid >> 6;
    int wm = wid & 1, wn = wid >> 1;

    f32x4 acc[2][4];
#pragma unroll
    for (int i = 0; i < 2; i++)
#pragma unroll
        for (int j = 0; j < 4; j++) acc[i][j] = (f32x4)(0.0f);

    for (int k0 = 0; k0 < Kd; k0 += 64) {
#pragma unroll
        for (int i = 0; i < 2; i++) {
            int c = tid + i * 256;
            int row = c >> 3, col = c & 7;
            int4 v = *reinterpret_cast<const int4*>(Ab + (long)(m0 + row) * Kd + k0 + col * 8);
            *reinterpret_cast<int4*>(&As[row * 72 + col * 8]) = v;
        }
#pragma unroll
        for (int i = 0; i < 4; i++) {
            int c = tid + i * 256;
            int row = c >> 3, col = c & 7;
            int4 v = *reinterpret_cast<const int4*>(Bb + (long)(n0 + row) * Kd + k0 + col * 8);
            *reinterpret_cast<int4*>(&Bs[row * 72 + col * 8]) = v;
        }
        __syncthreads();
#pragma unroll
        for (int kk = 0; kk < 64; kk += 32) {
            int klane = kk + 8 * (lane >> 4);
            half8 af[2], bfr[4];
#pragma unroll
            for (int fm = 0; fm < 2; fm++)
                af[fm] = *reinterpret_cast<const half8*>(&As[(wm * 32 + fm * 16 + (lane & 15)) * 72 + klane]);
#pragma unroll
            for (int fn = 0; fn < 4; fn++)
                bfr[fn] = *reinterpret_cast<const half8*>(&Bs[(wn * 64 + fn * 16 + (lane & 15)) * 72 + klane]);
#pragma unroll
            for (int fm = 0; fm < 2; fm++)
#pragma unroll
                for (int fn = 0; fn < 4; fn++)
                    acc[fm][fn] = __builtin_amdgcn_mfma_f32_16x16x32_f16(af[fm], bfr[fn], acc[fm][fn], 0, 0, 0);
        }
        __syncthreads();
    }

    long ob = (long)b * sOut;
#pragma unroll
    for (int fm = 0; fm < 2; fm++)
#pragma unroll
        for (int fn = 0; fn < 4; fn++)
#pragma unroll
            for (int r = 0; r < 4; r++) {
                int row = m0 + wm * 32 + fm * 16 + (lane >> 4) * 4 + r;
                int col = n0 + wn * 64 + fn * 16 + (lane & 15);
                Out[ob + (long)row * N + col] = (_Float16)acc[fm][fn][r];
            }
}

// ---------------- fused C + H + score kernel (both sides, XCD-swizzled, pipelined) ----
// side C (P < 512):  sc_c[b,n0+j] = sum_k whx[k]*tanh(Wxd[k,n0+j] + sum_p Wpt[k,p]*C[p,n0+j])
// side P (P >= 512): sc_p[b,n0+j] = sum_k whp[k]*tanh(Wpt[k,n0+j] + sum_l Wxd[k,l]*C[n0+j,l])
// XCD swizzle: x = P&7 selects XCD chunk; all tile-blocks of a batch share one XCD
// so the streamed tb/drug tiles stay L2-resident (T1).
// Pipeline: S/W tiles for step s+1 prefetched into regs during step s compute (T14).
__global__ __launch_bounds__(256)
void k_score_fused(const _Float16* __restrict__ drug_h, const _Float16* __restrict__ tb_h,
                   const _Float16* __restrict__ Wxd_h, const _Float16* __restrict__ Wpt_h,
                   const float* __restrict__ whx, const float* __restrict__ whp,
                   float* __restrict__ sc_c, float* __restrict__ sc_p)
{
    __shared__ alignas(16) _Float16 Rs[64 * 136];   // resident [64][128+8]
    __shared__ alignas(16) _Float16 Ss[64 * 136];   // streamed [64][128+8]
    __shared__ alignas(16) _Float16 Ws[64 * 72];    // W slice  [64k][64+8]
    __shared__ alignas(16) _Float16 Cts[64 * 76];   // C tile   [64res][64strm], stride 76 (conflict-free scatter)
    __shared__ float sred[8 * 64];
    __shared__ float wsh[64];

    int P = blockIdx.x;
    int tid = threadIdx.x;
    int lane = tid & 63;
    int wid = tid >> 6;
    int wm = wid & 1, wn = wid >> 1;

    int b, n0, nsteps, Ntot, sW;
    const _Float16 *R, *S, *W, *Add;
    const float* wv;
    float* out;
    if (P < 512) {
        int x = P & 7, j = P >> 3;            // x: XCD chunk; j in [0,64)
        b = x * 8 + (j >> 3);                  // batches [8x, 8x+8) on XCD x
        n0 = (j & 7) * 64;
        R = drug_h + (long)b * (LD * DD);
        S = tb_h   + (long)b * (LP * DD);
        W = Wpt_h  + (long)b * (KK * LP);  sW = LP;
        Add = Wxd_h + (long)b * (KK * LD); Ntot = LD;
        nsteps = LP / 64; wv = whx; out = sc_c + (long)b * LD;
    } else {
        int Q = P - 512;
        int x = Q & 7, j = Q >> 3;            // j in [0,128)
        b = x * 8 + (j >> 4);
        n0 = (j & 15) * 64;
        R = tb_h   + (long)b * (LP * DD);
        S = drug_h + (long)b * (LD * DD);
        W = Wxd_h  + (long)b * (KK * LD);  sW = LD;
        Add = Wpt_h + (long)b * (KK * LP); Ntot = LP;
        nsteps = LD / 64; wv = whp; out = sc_p + (long)b * LP;
    }

    // stage resident tile [64][128] + w
#pragma unroll
    for (int i = 0; i < 4; i++) {
        int c = tid + i * 256;
        int row = c >> 4, col8 = (c & 15) * 8;
        int4 v = *reinterpret_cast<const int4*>(R + (long)(n0 + row) * DD + col8);
        *reinterpret_cast<int4*>(&Rs[row * 136 + col8]) = v;
    }
    if (tid < 64) wsh[tid] = wv[tid];

    // register prefetch of S/W tiles (step 0)
    int4 pS[4], pW[2];
    auto loadS = [&](int ss) {
#pragma unroll
        for (int i = 0; i < 4; i++) {
            int c = tid + i * 256;
            int row = c >> 4, col8 = (c & 15) * 8;
            pS[i] = *reinterpret_cast<const int4*>(S + (long)(ss * 64 + row) * DD + col8);
        }
#pragma unroll
        for (int i = 0; i < 2; i++) {
            int c = tid + i * 256;
            int row = c >> 3, col8 = (c & 7) * 8;
            pW[i] = *reinterpret_cast<const int4*>(W + (long)row * sW + ss * 64 + col8);
        }
    };
    loadS(0);

    f32x4 acc2[2][2];
#pragma unroll
    for (int i = 0; i < 2; i++)
#pragma unroll
        for (int j = 0; j < 2; j++) acc2[i][j] = (f32x4)(0.0f);

    for (int s = 0; s < nsteps; s++) {
        __syncthreads();                  // (C) prev GEMM2 done; LDS buffers free
        // write prefetched regs -> LDS
#pragma unroll
        for (int i = 0; i < 4; i++) {
            int c = tid + i * 256;
            int row = c >> 4, col8 = (c & 15) * 8;
            *reinterpret_cast<int4*>(&Ss[row * 136 + col8]) = pS[i];
        }
#pragma unroll
        for (int i = 0; i < 2; i++) {
            int c = tid + i * 256;
            int row = c >> 3, col8 = (c & 7) * 8;
            *reinterpret_cast<int4*>(&Ws[row * 72 + col8]) = pW[i];
        }
        __syncthreads();                  // (A) staging visible (covers Rs/wsh at s=0)
        if (s + 1 < nsteps) loadS(s + 1); // prefetch next step; latency hides under compute

        // GEMM1: a1[res, strm] = sum_d Rs[res,d]*Ss[strm,d]
        f32x4 a1[2][2];
#pragma unroll
        for (int i = 0; i < 2; i++)
#pragma unroll
            for (int j = 0; j < 2; j++) a1[i][j] = (f32x4)(0.0f);
#pragma unroll
        for (int kk = 0; kk < 4; kk++) {
            int klane = kk * 32 + 8 * (lane >> 4);
            half8 af[2], bf[2];
#pragma unroll
            for (int fm = 0; fm < 2; fm++)
                af[fm] = *reinterpret_cast<const half8*>(&Rs[(wm * 32 + fm * 16 + (lane & 15)) * 136 + klane]);
#pragma unroll
            for (int fn = 0; fn < 2; fn++)
                bf[fn] = *reinterpret_cast<const half8*>(&Ss[(wn * 32 + fn * 16 + (lane & 15)) * 136 + klane]);
#pragma unroll
            for (int fm = 0; fm < 2; fm++)
#pragma unroll
                for (int fn = 0; fn < 2; fn++)
                    a1[fm][fn] = __builtin_amdgcn_mfma_f32_16x16x32_f16(af[fm], bf[fn], a1[fm][fn], 0, 0, 0);
        }
        // tanh -> Cts [res][strm] (stride 76: lane-groups land on disjoint bank octets)
#pragma unroll
        for (int fm = 0; fm < 2; fm++)
#pragma unroll
            for (int fn = 0; fn < 2; fn++)
#pragma unroll
                for (int r = 0; r < 4; r++) {
                    int res  = wm * 32 + fm * 16 + (lane >> 4) * 4 + r;
                    int strm = wn * 32 + fn * 16 + (lane & 15);
                    Cts[res * 76 + strm] = (_Float16)ftanh(a1[fm][fn][r]);
                }
        __syncthreads();                  // (B) Cts ready

        // GEMM2: acc2[k, res] += sum_strm Ws[k,strm]*Cts[res,strm]
#pragma unroll
        for (int kk = 0; kk < 2; kk++) {
            int klane = kk * 32 + 8 * (lane >> 4);
            half8 af[2], bf[2];
#pragma unroll
            for (int fm = 0; fm < 2; fm++)
                af[fm] = *reinterpret_cast<const half8*>(&Ws[(wm * 32 + fm * 16 + (lane & 15)) * 72 + klane]);
#pragma unroll
            for (int fn = 0; fn < 2; fn++)
                bf[fn] = *reinterpret_cast<const half8*>(&Cts[(wn * 32 + fn * 16 + (lane & 15)) * 76 + klane]);
#pragma unroll
            for (int fm = 0; fm < 2; fm++)
#pragma unroll
                for (int fn = 0; fn < 2; fn++)
                    acc2[fm][fn] = __builtin_amdgcn_mfma_f32_16x16x32_f16(af[fm], bf[fn], acc2[fm][fn], 0, 0, 0);
        }
    }

    // epilogue: + Add, tanh, dot w, block reduce over k
    float ps[2] = {0.f, 0.f};
#pragma unroll
    for (int fm = 0; fm < 2; fm++)
#pragma unroll
        for (int fn = 0; fn < 2; fn++)
#pragma unroll
            for (int r = 0; r < 4; r++) {
                int k   = wm * 32 + fm * 16 + (lane >> 4) * 4 + r;
                int col = wn * 32 + fn * 16 + (lane & 15);
                float v = ftanh(acc2[fm][fn][r] + (float)Add[(long)k * Ntot + n0 + col]);
                ps[fn] += wsh[k] * v;
            }
#pragma unroll
    for (int fn = 0; fn < 2; fn++)
        sred[(wm * 4 + (lane >> 4)) * 64 + wn * 32 + fn * 16 + (lane & 15)] = ps[fn];
    __syncthreads();
    if (tid < 64) {
        float sacc = 0.f;
#pragma unroll
        for (int j = 0; j < 8; j++) sacc += sred[j * 64 + tid];
        out[n0 + tid] = sacc;
    }
}

// ---------------- softmax over scores ----------------
__device__ __forceinline__ float wred_max(float v) {
#pragma unroll
    for (int off = 32; off > 0; off >>= 1) v = fmaxf(v, __shfl_xor(v, off, 64));
    return v;
}
__device__ __forceinline__ float wred_sum(float v) {
#pragma unroll
    for (int off = 32; off > 0; off >>= 1) v += __shfl_xor(v, off, 64);
    return v;
}

__global__ __launch_bounds__(1024)
void k_soft(const float* __restrict__ scc, const float* __restrict__ scp,
            float* __restrict__ ac, float* __restrict__ ap)
{
    __shared__ float r16[16];
    int b = blockIdx.x, tid = threadIdx.x;
    int lane = tid & 63, wid = tid >> 6;

    float s = (tid < 512) ? scc[b * 512 + tid] : -3.4e38f;
    float m = wred_max(s);
    if (lane == 0) r16[wid] = m;
    __syncthreads();
    m = r16[0];
#pragma unroll
    for (int i = 1; i < 16; i++) m = fmaxf(m, r16[i]);
    float e = (tid < 512) ? __expf(s - m) : 0.f;
    __syncthreads();
    float t = wred_sum(e);
    if (lane == 0) r16[wid] = t;
    __syncthreads();
    float sum = 0.f;
#pragma unroll
    for (int i = 0; i < 16; i++) sum += r16[i];
    if (tid < 512) ac[b * 512 + tid] = e / sum;
    __syncthreads();

    float s2 = scp[b * 1024 + tid];
    float m2 = wred_max(s2);
    if (lane == 0) r16[wid] = m2;
    __syncthreads();
    m2 = r16[0];
#pragma unroll
    for (int i = 1; i < 16; i++) m2 = fmaxf(m2, r16[i]);
    float e2 = __expf(s2 - m2);
    __syncthreads();
    float t2 = wred_sum(e2);
    if (lane == 0) r16[wid] = t2;
    __syncthreads();
    float sum2 = 0.f;
#pragma unroll
    for (int i = 0; i < 16; i++) sum2 += r16[i];
    ap[b * 1024 + tid] = e2 / sum2;
}

// ---------------- weighted sums: out[b,d] = sum_l a[l] * X[b,l,d] ----------------
__global__ __launch_bounds__(512)
void k_wsum(const _Float16* __restrict__ drug_h, const _Float16* __restrict__ targ_h,
            const float* __restrict__ ac, const float* __restrict__ ap,
            float* __restrict__ out)
{
    __shared__ float ash[1024];
    __shared__ float red[32 * 128];
    int b = blockIdx.x, side = blockIdx.y;
    int L = side ? LP : LD;
    const _Float16* X = side ? targ_h : drug_h;
    const float* a = side ? ap : ac;
    float* ob = out + side * 8192 + b * 128;
    int tid = threadIdx.x;

    for (int i = tid; i < L; i += 512) ash[i] = a[(long)b * L + i];
    __syncthreads();

    int col8 = tid & 15, rg = tid >> 4;
    float accv[8];
#pragma unroll
    for (int j = 0; j < 8; j++) accv[j] = 0.f;
    const _Float16* Xb = X + (long)b * L * 128;
    for (int l = rg; l < L; l += 32) {
        half8 v = *reinterpret_cast<const half8*>(&Xb[l * 128 + col8 * 8]);
        float av = ash[l];
#pragma unroll
        for (int j = 0; j < 8; j++) accv[j] += av * (float)v[j];
    }
#pragma unroll
    for (int j = 0; j < 8; j++) red[rg * 128 + col8 * 8 + j] = accv[j];
    __syncthreads();
    if (tid < 128) {
        float s = 0.f;
#pragma unroll
        for (int g = 0; g < 32; g++) s += red[g * 128 + tid];
        ob[tid] = s;
    }
}

// ---------------- launch ----------------
extern "C" void kernel_launch(void* const* d_in, const int* in_sizes, int n_in,
                              void* d_out, int out_size, void* d_ws, size_t ws_size,
                              hipStream_t stream) {
    (void)in_sizes; (void)n_in; (void)out_size;
    const float* drug   = (const float*)d_in[0];
    const float* target = (const float*)d_in[1];
    const float* Wb     = (const float*)d_in[2];
    const float* Wx     = (const float*)d_in[3];
    const float* Wp     = (const float*)d_in[4];
    const float* whx    = (const float*)d_in[5];
    const float* whp    = (const float*)d_in[6];

    char* w = (char*)d_ws;
    size_t off = 0;
    auto takeb = [&](size_t bytes) {
        void* p = (void*)(w + off);
        off += (bytes + 255) & ~(size_t)255;
        return p;
    };
    _Float16* drug_h = (_Float16*)takeb((size_t)NB * LD * DD * 2);
    _Float16* targ_h = (_Float16*)takeb((size_t)NB * LP * DD * 2);
    _Float16* WbT_h  = (_Float16*)takeb(128 * 128 * 2);
    _Float16* Wx_h   = (_Float16*)takeb(64 * 128 * 2);
    _Float16* Wp_h   = (_Float16*)takeb(64 * 128 * 2);
    _Float16* tb_h   = (_Float16*)takeb((size_t)NB * LP * DD * 2);
    _Float16* Wxd_h  = (_Float16*)takeb((size_t)NB * KK * LD * 2);
    _Float16* Wpt_h  = (_Float16*)takeb((size_t)NB * KK * LP * 2);
    float*    sc_c   = (float*)takeb((size_t)NB * LD * 4);
    float*    sc_p   = (float*)takeb((size_t)NB * LP * 4);
    float*    a_c    = (float*)takeb((size_t)NB * LD * 4);
    float*    a_p    = (float*)takeb((size_t)NB * LP * 4);

    if (off > ws_size) {                 // workspace shortfall -> sentinel (absmax ~1000)
        k_sentinel<<<1, 64, 0, stream>>>((float*)d_out);
        return;
    }

    k_conv<<<1024, 256, 0, stream>>>(drug,   drug_h, NB * LD * DD);
    k_conv<<<1024, 256, 0, stream>>>(target, targ_h, NB * LP * DD);
    k_conv<<<16, 256, 0, stream>>>(Wx, Wx_h, 64 * 128);
    k_conv<<<16, 256, 0, stream>>>(Wp, Wp_h, 64 * 128);
    k_wbt<<<64, 256, 0, stream>>>(Wb, WbT_h);

    // tb[p,d] = sum_e target[p,e] * WbT[d,e]            M=LP  N=128 Kd=128
    k_gemm<<<dim3(NB * (LP / 64)), 256, 0, stream>>>(
        targ_h, (long)LP * DD, WbT_h, 0, tb_h, (long)LP * DD, 128, 128, LP / 64, 1);
    // Wxd[k,l] = sum_d Wx[k,d] * drug[l,d]              M=64  N=LD  Kd=128
    k_gemm<<<dim3(NB * (LD / 128)), 256, 0, stream>>>(
        Wx_h, 0, drug_h, (long)LD * DD, Wxd_h, (long)KK * LD, LD, 128, 1, LD / 128);
    // Wpt[k,p] = sum_e Wp[k,e] * target[p,e]            M=64  N=LP  Kd=128
    k_gemm<<<dim3(NB * (LP / 128)), 256, 0, stream>>>(
        Wp_h, 0, targ_h, (long)LP * DD, Wpt_h, (long)KK * LP, LP, 128, 1, LP / 128);

    // fused: C recomputed per side in-LDS; scores out directly
    k_score_fused<<<dim3(512 + 1024), 256, 0, stream>>>(
        drug_h, tb_h, Wxd_h, Wpt_h, whx, whp, sc_c, sc_p);

    k_soft<<<NB, 1024, 0, stream>>>(sc_c, sc_p, a_c, a_p);
    k_wsum<<<dim3(NB, 2), 512, 0, stream>>>(drug_h, targ_h, a_c, a_p, (float*)d_out);
}

// Round 11
// 129.064 us; speedup vs baseline: 1.4053x; 1.4053x over previous
//
#include <hip/hip_runtime.h>
#include <hip/hip_bf16.h>
#include <math.h>

#define NB 64
#define LD 512
#define LP 1024
#define DD 128
#define KK 64

using half8 = __attribute__((ext_vector_type(8))) _Float16;
using half4 = __attribute__((ext_vector_type(4))) _Float16;
using f32x4 = __attribute__((ext_vector_type(4))) float;

// fast tanh: 1 - 2/(e^{2x}+1); inf-safe both tails
__device__ __forceinline__ float ftanh(float x) {
    float e = __expf(2.0f * x);
    return 1.0f - 2.0f / (e + 1.0f);
}

// ---------------- conversion kernels ----------------
__global__ void k_conv(const float* __restrict__ in, _Float16* __restrict__ out, int n) {
    int i = (blockIdx.x * blockDim.x + threadIdx.x) * 4;
    int stride = gridDim.x * blockDim.x * 4;
    for (; i < n; i += stride) {
        float4 v = *reinterpret_cast<const float4*>(in + i);
        half4 h;
        h.x = (_Float16)v.x; h.y = (_Float16)v.y; h.z = (_Float16)v.z; h.w = (_Float16)v.w;
        *reinterpret_cast<half4*>(out + i) = h;
    }
}

__global__ void k_wbt(const float* __restrict__ Wb, _Float16* __restrict__ WbT) {
    int t = blockIdx.x * 256 + threadIdx.x;
    int d = t >> 7, e = t & 127;
    WbT[t] = (_Float16)Wb[e * 128 + d];
}

__global__ void k_sentinel(float* out) {
    if (threadIdx.x == 0 && blockIdx.x == 0) out[0] = 1000.0f;
}

// ---------------- plain batched NT GEMM, fp16 in/out (tb, Wxd, Wpt) ----------------
__global__ __launch_bounds__(256)
void k_gemm(const _Float16* __restrict__ A, long sA,
            const _Float16* __restrict__ Bm, long sB,
            _Float16* __restrict__ Out, long sOut,
            int N, int Kd, int tilesM, int tilesN)
{
    __shared__ alignas(16) _Float16 smem[64 * 72 + 128 * 72];
    _Float16* As = smem;
    _Float16* Bs = smem + 64 * 72;

    int bid = blockIdx.x;
    int tpb = tilesM * tilesN;
    int b = bid / tpb;
    int t = bid % tpb;
    int m0 = (t / tilesN) * 64;
    int n0 = (t % tilesN) * 128;

    const _Float16* Ab = A + (long)b * sA;
    const _Float16* Bb = Bm + (long)b * sB;

    int tid = threadIdx.x;
    int lane = tid & 63;
    int wid = tid >> 6;
    int wm = wid & 1, wn = wid >> 1;

    f32x4 acc[2][4];
#pragma unroll
    for (int i = 0; i < 2; i++)
#pragma unroll
        for (int j = 0; j < 4; j++) acc[i][j] = (f32x4)(0.0f);

    for (int k0 = 0; k0 < Kd; k0 += 64) {
#pragma unroll
        for (int i = 0; i < 2; i++) {
            int c = tid + i * 256;
            int row = c >> 3, col = c & 7;
            int4 v = *reinterpret_cast<const int4*>(Ab + (long)(m0 + row) * Kd + k0 + col * 8);
            *reinterpret_cast<int4*>(&As[row * 72 + col * 8]) = v;
        }
#pragma unroll
        for (int i = 0; i < 4; i++) {
            int c = tid + i * 256;
            int row = c >> 3, col = c & 7;
            int4 v = *reinterpret_cast<const int4*>(Bb + (long)(n0 + row) * Kd + k0 + col * 8);
            *reinterpret_cast<int4*>(&Bs[row * 72 + col * 8]) = v;
        }
        __syncthreads();
#pragma unroll
        for (int kk = 0; kk < 64; kk += 32) {
            int klane = kk + 8 * (lane >> 4);
            half8 af[2], bfr[4];
#pragma unroll
            for (int fm = 0; fm < 2; fm++)
                af[fm] = *reinterpret_cast<const half8*>(&As[(wm * 32 + fm * 16 + (lane & 15)) * 72 + klane]);
#pragma unroll
            for (int fn = 0; fn < 4; fn++)
                bfr[fn] = *reinterpret_cast<const half8*>(&Bs[(wn * 64 + fn * 16 + (lane & 15)) * 72 + klane]);
#pragma unroll
            for (int fm = 0; fm < 2; fm++)
#pragma unroll
                for (int fn = 0; fn < 4; fn++)
                    acc[fm][fn] = __builtin_amdgcn_mfma_f32_16x16x32_f16(af[fm], bfr[fn], acc[fm][fn], 0, 0, 0);
        }
        __syncthreads();
    }

    long ob = (long)b * sOut;
#pragma unroll
    for (int fm = 0; fm < 2; fm++)
#pragma unroll
        for (int fn = 0; fn < 4; fn++)
#pragma unroll
            for (int r = 0; r < 4; r++) {
                int row = m0 + wm * 32 + fm * 16 + (lane >> 4) * 4 + r;
                int col = n0 + wn * 64 + fn * 16 + (lane & 15);
                Out[ob + (long)row * N + col] = (_Float16)acc[fm][fn][r];
            }
}

// ---------------- fused C + H + score kernel (both sides, XCD-swizzled) ----------------
// side C (P < 512):  sc_c[b,n0+j] = sum_k whx[k]*tanh(Wxd[k,n0+j] + sum_p Wpt[k,p]*C[p,n0+j])
// side P (P >= 512): sc_p[b,n0+j] = sum_k whp[k]*tanh(Wpt[k,n0+j] + sum_l Wxd[k,l]*C[n0+j,l])
// XCD swizzle (T1): x = P&7 selects XCD chunk; all tile-blocks of a batch share one XCD.
// Resident tile held as MFMA A-fragments in REGISTERS (no Rs in LDS) -> 38.1 KB LDS, 4 blocks/CU.
__global__ __launch_bounds__(256)
void k_score_fused(const _Float16* __restrict__ drug_h, const _Float16* __restrict__ tb_h,
                   const _Float16* __restrict__ Wxd_h, const _Float16* __restrict__ Wpt_h,
                   const float* __restrict__ whx, const float* __restrict__ whp,
                   float* __restrict__ sc_c, float* __restrict__ sc_p)
{
    __shared__ alignas(16) _Float16 Ss[64 * 136];   // streamed [64][128+8]
    __shared__ alignas(16) _Float16 Ws[64 * 72];    // W slice  [64k][64+8]
    __shared__ alignas(16) _Float16 Cts[64 * 72];   // C tile   [64res][64strm+8] (read-optimal stride)
    __shared__ float sred[8 * 64];
    __shared__ float wsh[64];

    int P = blockIdx.x;
    int tid = threadIdx.x;
    int lane = tid & 63;
    int wid = tid >> 6;
    int wm = wid & 1, wn = wid >> 1;

    int b, n0, nsteps, Ntot, sW;
    const _Float16 *R, *S, *W, *Add;
    const float* wv;
    float* out;
    if (P < 512) {
        int x = P & 7, j = P >> 3;            // x: XCD chunk; j in [0,64)
        b = x * 8 + (j >> 3);                  // batches [8x, 8x+8) on XCD x
        n0 = (j & 7) * 64;
        R = drug_h + (long)b * (LD * DD);
        S = tb_h   + (long)b * (LP * DD);
        W = Wpt_h  + (long)b * (KK * LP);  sW = LP;
        Add = Wxd_h + (long)b * (KK * LD); Ntot = LD;
        nsteps = LP / 64; wv = whx; out = sc_c + (long)b * LD;
    } else {
        int Q = P - 512;
        int x = Q & 7, j = Q >> 3;            // j in [0,128)
        b = x * 8 + (j >> 4);
        n0 = (j & 15) * 64;
        R = tb_h   + (long)b * (LP * DD);
        S = drug_h + (long)b * (LD * DD);
        W = Wxd_h  + (long)b * (KK * LD);  sW = LD;
        Add = Wpt_h + (long)b * (KK * LP); Ntot = LP;
        nsteps = LD / 64; wv = whp; out = sc_p + (long)b * LP;
    }

    // resident A-fragments in registers (loaded once; rows never change across steps)
    half8 af[2][4];
#pragma unroll
    for (int fm = 0; fm < 2; fm++)
#pragma unroll
        for (int kk = 0; kk < 4; kk++) {
            int row = n0 + wm * 32 + fm * 16 + (lane & 15);
            int col = kk * 32 + 8 * (lane >> 4);
            af[fm][kk] = *reinterpret_cast<const half8*>(R + (long)row * DD + col);
        }
    if (tid < 64) wsh[tid] = wv[tid];

    f32x4 acc2[2][2];
#pragma unroll
    for (int i = 0; i < 2; i++)
#pragma unroll
        for (int j = 0; j < 2; j++) acc2[i][j] = (f32x4)(0.0f);

    for (int s = 0; s < nsteps; s++) {
        __syncthreads();                  // (C) prev GEMM2 done; Ss/Ws free
        // stage stream tile [64][128]
#pragma unroll
        for (int i = 0; i < 4; i++) {
            int c = tid + i * 256;
            int row = c >> 4, col8 = (c & 15) * 8;
            int4 v = *reinterpret_cast<const int4*>(S + (long)(s * 64 + row) * DD + col8);
            *reinterpret_cast<int4*>(&Ss[row * 136 + col8]) = v;
        }
        // stage W slice [64][64]
#pragma unroll
        for (int i = 0; i < 2; i++) {
            int c = tid + i * 256;
            int row = c >> 3, col8 = (c & 7) * 8;
            int4 v = *reinterpret_cast<const int4*>(W + (long)row * sW + s * 64 + col8);
            *reinterpret_cast<int4*>(&Ws[row * 72 + col8]) = v;
        }
        __syncthreads();                  // (A) staging visible (covers wsh at s=0)

        // GEMM1: a1[res, strm] = sum_d af[res,d]*Ss[strm,d]
        f32x4 a1[2][2];
#pragma unroll
        for (int i = 0; i < 2; i++)
#pragma unroll
            for (int j = 0; j < 2; j++) a1[i][j] = (f32x4)(0.0f);
#pragma unroll
        for (int kk = 0; kk < 4; kk++) {
            int klane = kk * 32 + 8 * (lane >> 4);
            half8 bf[2];
#pragma unroll
            for (int fn = 0; fn < 2; fn++)
                bf[fn] = *reinterpret_cast<const half8*>(&Ss[(wn * 32 + fn * 16 + (lane & 15)) * 136 + klane]);
#pragma unroll
            for (int fm = 0; fm < 2; fm++)
#pragma unroll
                for (int fn = 0; fn < 2; fn++)
                    a1[fm][fn] = __builtin_amdgcn_mfma_f32_16x16x32_f16(af[fm][kk], bf[fn], a1[fm][fn], 0, 0, 0);
        }
        // tanh -> Cts [res][strm] (stride 72: b128 read path 2-way/free; b16 scatter 4-way)
#pragma unroll
        for (int fm = 0; fm < 2; fm++)
#pragma unroll
            for (int fn = 0; fn < 2; fn++)
#pragma unroll
                for (int r = 0; r < 4; r++) {
                    int res  = wm * 32 + fm * 16 + (lane >> 4) * 4 + r;
                    int strm = wn * 32 + fn * 16 + (lane & 15);
                    Cts[res * 72 + strm] = (_Float16)ftanh(a1[fm][fn][r]);
                }
        __syncthreads();                  // (B) Cts ready

        // GEMM2: acc2[k, res] += sum_strm Ws[k,strm]*Cts[res,strm]
#pragma unroll
        for (int kk = 0; kk < 2; kk++) {
            int klane = kk * 32 + 8 * (lane >> 4);
            half8 aw[2], bf[2];
#pragma unroll
            for (int fm = 0; fm < 2; fm++)
                aw[fm] = *reinterpret_cast<const half8*>(&Ws[(wm * 32 + fm * 16 + (lane & 15)) * 72 + klane]);
#pragma unroll
            for (int fn = 0; fn < 2; fn++)
                bf[fn] = *reinterpret_cast<const half8*>(&Cts[(wn * 32 + fn * 16 + (lane & 15)) * 72 + klane]);
#pragma unroll
            for (int fm = 0; fm < 2; fm++)
#pragma unroll
                for (int fn = 0; fn < 2; fn++)
                    acc2[fm][fn] = __builtin_amdgcn_mfma_f32_16x16x32_f16(aw[fm], bf[fn], acc2[fm][fn], 0, 0, 0);
        }
    }

    // epilogue: + Add, tanh, dot w, block reduce over k
    float ps[2] = {0.f, 0.f};
#pragma unroll
    for (int fm = 0; fm < 2; fm++)
#pragma unroll
        for (int fn = 0; fn < 2; fn++)
#pragma unroll
            for (int r = 0; r < 4; r++) {
                int k   = wm * 32 + fm * 16 + (lane >> 4) * 4 + r;
                int col = wn * 32 + fn * 16 + (lane & 15);
                float v = ftanh(acc2[fm][fn][r] + (float)Add[(long)k * Ntot + n0 + col]);
                ps[fn] += wsh[k] * v;
            }
#pragma unroll
    for (int fn = 0; fn < 2; fn++)
        sred[(wm * 4 + (lane >> 4)) * 64 + wn * 32 + fn * 16 + (lane & 15)] = ps[fn];
    __syncthreads();
    if (tid < 64) {
        float sacc = 0.f;
#pragma unroll
        for (int j = 0; j < 8; j++) sacc += sred[j * 64 + tid];
        out[n0 + tid] = sacc;
    }
}

// ---------------- softmax over scores ----------------
__device__ __forceinline__ float wred_max(float v) {
#pragma unroll
    for (int off = 32; off > 0; off >>= 1) v = fmaxf(v, __shfl_xor(v, off, 64));
    return v;
}
__device__ __forceinline__ float wred_sum(float v) {
#pragma unroll
    for (int off = 32; off > 0; off >>= 1) v += __shfl_xor(v, off, 64);
    return v;
}

__global__ __launch_bounds__(1024)
void k_soft(const float* __restrict__ scc, const float* __restrict__ scp,
            float* __restrict__ ac, float* __restrict__ ap)
{
    __shared__ float r16[16];
    int b = blockIdx.x, tid = threadIdx.x;
    int lane = tid & 63, wid = tid >> 6;

    float s = (tid < 512) ? scc[b * 512 + tid] : -3.4e38f;
    float m = wred_max(s);
    if (lane == 0) r16[wid] = m;
    __syncthreads();
    m = r16[0];
#pragma unroll
    for (int i = 1; i < 16; i++) m = fmaxf(m, r16[i]);
    float e = (tid < 512) ? __expf(s - m) : 0.f;
    __syncthreads();
    float t = wred_sum(e);
    if (lane == 0) r16[wid] = t;
    __syncthreads();
    float sum = 0.f;
#pragma unroll
    for (int i = 0; i < 16; i++) sum += r16[i];
    if (tid < 512) ac[b * 512 + tid] = e / sum;
    __syncthreads();

    float s2 = scp[b * 1024 + tid];
    float m2 = wred_max(s2);
    if (lane == 0) r16[wid] = m2;
    __syncthreads();
    m2 = r16[0];
#pragma unroll
    for (int i = 1; i < 16; i++) m2 = fmaxf(m2, r16[i]);
    float e2 = __expf(s2 - m2);
    __syncthreads();
    float t2 = wred_sum(e2);
    if (lane == 0) r16[wid] = t2;
    __syncthreads();
    float sum2 = 0.f;
#pragma unroll
    for (int i = 0; i < 16; i++) sum2 += r16[i];
    ap[b * 1024 + tid] = e2 / sum2;
}

// ---------------- weighted sums: out[b,d] = sum_l a[l] * X[b,l,d] ----------------
__global__ __launch_bounds__(512)
void k_wsum(const _Float16* __restrict__ drug_h, const _Float16* __restrict__ targ_h,
            const float* __restrict__ ac, const float* __restrict__ ap,
            float* __restrict__ out)
{
    __shared__ float ash[1024];
    __shared__ float red[32 * 128];
    int b = blockIdx.x, side = blockIdx.y;
    int L = side ? LP : LD;
    const _Float16* X = side ? targ_h : drug_h;
    const float* a = side ? ap : ac;
    float* ob = out + side * 8192 + b * 128;
    int tid = threadIdx.x;

    for (int i = tid; i < L; i += 512) ash[i] = a[(long)b * L + i];
    __syncthreads();

    int col8 = tid & 15, rg = tid >> 4;
    float accv[8];
#pragma unroll
    for (int j = 0; j < 8; j++) accv[j] = 0.f;
    const _Float16* Xb = X + (long)b * L * 128;
    for (int l = rg; l < L; l += 32) {
        half8 v = *reinterpret_cast<const half8*>(&Xb[l * 128 + col8 * 8]);
        float av = ash[l];
#pragma unroll
        for (int j = 0; j < 8; j++) accv[j] += av * (float)v[j];
    }
#pragma unroll
    for (int j = 0; j < 8; j++) red[rg * 128 + col8 * 8 + j] = accv[j];
    __syncthreads();
    if (tid < 128) {
        float s = 0.f;
#pragma unroll
        for (int g = 0; g < 32; g++) s += red[g * 128 + tid];
        ob[tid] = s;
    }
}

// ---------------- launch ----------------
extern "C" void kernel_launch(void* const* d_in, const int* in_sizes, int n_in,
                              void* d_out, int out_size, void* d_ws, size_t ws_size,
                              hipStream_t stream) {
    (void)in_sizes; (void)n_in; (void)out_size;
    const float* drug   = (const float*)d_in[0];
    const float* target = (const float*)d_in[1];
    const float* Wb     = (const float*)d_in[2];
    const float* Wx     = (const float*)d_in[3];
    const float* Wp     = (const float*)d_in[4];
    const float* whx    = (const float*)d_in[5];
    const float* whp    = (const float*)d_in[6];

    char* w = (char*)d_ws;
    size_t off = 0;
    auto takeb = [&](size_t bytes) {
        void* p = (void*)(w + off);
        off += (bytes + 255) & ~(size_t)255;
        return p;
    };
    _Float16* drug_h = (_Float16*)takeb((size_t)NB * LD * DD * 2);
    _Float16* targ_h = (_Float16*)takeb((size_t)NB * LP * DD * 2);
    _Float16* WbT_h  = (_Float16*)takeb(128 * 128 * 2);
    _Float16* Wx_h   = (_Float16*)takeb(64 * 128 * 2);
    _Float16* Wp_h   = (_Float16*)takeb(64 * 128 * 2);
    _Float16* tb_h   = (_Float16*)takeb((size_t)NB * LP * DD * 2);
    _Float16* Wxd_h  = (_Float16*)takeb((size_t)NB * KK * LD * 2);
    _Float16* Wpt_h  = (_Float16*)takeb((size_t)NB * KK * LP * 2);
    float*    sc_c   = (float*)takeb((size_t)NB * LD * 4);
    float*    sc_p   = (float*)takeb((size_t)NB * LP * 4);
    float*    a_c    = (float*)takeb((size_t)NB * LD * 4);
    float*    a_p    = (float*)takeb((size_t)NB * LP * 4);

    if (off > ws_size) {                 // workspace shortfall -> sentinel (absmax ~1000)
        k_sentinel<<<1, 64, 0, stream>>>((float*)d_out);
        return;
    }

    k_conv<<<1024, 256, 0, stream>>>(drug,   drug_h, NB * LD * DD);
    k_conv<<<1024, 256, 0, stream>>>(target, targ_h, NB * LP * DD);
    k_conv<<<16, 256, 0, stream>>>(Wx, Wx_h, 64 * 128);
    k_conv<<<16, 256, 0, stream>>>(Wp, Wp_h, 64 * 128);
    k_wbt<<<64, 256, 0, stream>>>(Wb, WbT_h);

    // tb[p,d] = sum_e target[p,e] * WbT[d,e]            M=LP  N=128 Kd=128
    k_gemm<<<dim3(NB * (LP / 64)), 256, 0, stream>>>(
        targ_h, (long)LP * DD, WbT_h, 0, tb_h, (long)LP * DD, 128, 128, LP / 64, 1);
    // Wxd[k,l] = sum_d Wx[k,d] * drug[l,d]              M=64  N=LD  Kd=128
    k_gemm<<<dim3(NB * (LD / 128)), 256, 0, stream>>>(
        Wx_h, 0, drug_h, (long)LD * DD, Wxd_h, (long)KK * LD, LD, 128, 1, LD / 128);
    // Wpt[k,p] = sum_e Wp[k,e] * target[p,e]            M=64  N=LP  Kd=128
    k_gemm<<<dim3(NB * (LP / 128)), 256, 0, stream>>>(
        Wp_h, 0, targ_h, (long)LP * DD, Wpt_h, (long)KK * LP, LP, 128, 1, LP / 128);

    // fused: C recomputed per side in-LDS; scores out directly
    k_score_fused<<<dim3(512 + 1024), 256, 0, stream>>>(
        drug_h, tb_h, Wxd_h, Wpt_h, whx, whp, sc_c, sc_p);

    k_soft<<<NB, 1024, 0, stream>>>(sc_c, sc_p, a_c, a_p);
    k_wsum<<<dim3(NB, 2), 512, 0, stream>>>(drug_h, targ_h, a_c, a_p, (float*)d_out);
}

// Round 12
// 119.599 us; speedup vs baseline: 1.5166x; 1.0791x over previous
//
#include <hip/hip_runtime.h>
#include <hip/hip_bf16.h>
#include <math.h>

#define NB 64
#define LD 512
#define LP 1024
#define DD 128
#define KK 64

using half8 = __attribute__((ext_vector_type(8))) _Float16;
using half4 = __attribute__((ext_vector_type(4))) _Float16;
using f32x4 = __attribute__((ext_vector_type(4))) float;

// fast tanh: 1 - 2*rcp(e^{2x}+1) via v_rcp_f32 (no IEEE div sequence).
// tails: x>>0 -> e=inf -> rcp=0 -> 1 ; x<<0 -> e=0 -> rcp(1)=1 -> -1.
__device__ __forceinline__ float ftanh(float x) {
    float e = __expf(2.0f * x);
    return 1.0f - 2.0f * __builtin_amdgcn_rcpf(e + 1.0f);
}

// ---------------- conversion kernels ----------------
__global__ void k_conv(const float* __restrict__ in, _Float16* __restrict__ out, int n) {
    int i = (blockIdx.x * blockDim.x + threadIdx.x) * 4;
    int stride = gridDim.x * blockDim.x * 4;
    for (; i < n; i += stride) {
        float4 v = *reinterpret_cast<const float4*>(in + i);
        half4 h;
        h.x = (_Float16)v.x; h.y = (_Float16)v.y; h.z = (_Float16)v.z; h.w = (_Float16)v.w;
        *reinterpret_cast<half4*>(out + i) = h;
    }
}

__global__ void k_wbt(const float* __restrict__ Wb, _Float16* __restrict__ WbT) {
    int t = blockIdx.x * 256 + threadIdx.x;
    int d = t >> 7, e = t & 127;
    WbT[t] = (_Float16)Wb[e * 128 + d];
}

__global__ void k_sentinel(float* out) {
    if (threadIdx.x == 0 && blockIdx.x == 0) out[0] = 1000.0f;
}

// ---------------- plain batched NT GEMM, fp16 in/out (tb, Wxd, Wpt) ----------------
__global__ __launch_bounds__(256)
void k_gemm(const _Float16* __restrict__ A, long sA,
            const _Float16* __restrict__ Bm, long sB,
            _Float16* __restrict__ Out, long sOut,
            int N, int Kd, int tilesM, int tilesN)
{
    __shared__ alignas(16) _Float16 smem[64 * 72 + 128 * 72];
    _Float16* As = smem;
    _Float16* Bs = smem + 64 * 72;

    int bid = blockIdx.x;
    int tpb = tilesM * tilesN;
    int b = bid / tpb;
    int t = bid % tpb;
    int m0 = (t / tilesN) * 64;
    int n0 = (t % tilesN) * 128;

    const _Float16* Ab = A + (long)b * sA;
    const _Float16* Bb = Bm + (long)b * sB;

    int tid = threadIdx.x;
    int lane = tid & 63;
    int wid = tid >> 6;
    int wm = wid & 1, wn = wid >> 1;

    f32x4 acc[2][4];
#pragma unroll
    for (int i = 0; i < 2; i++)
#pragma unroll
        for (int j = 0; j < 4; j++) acc[i][j] = (f32x4)(0.0f);

    for (int k0 = 0; k0 < Kd; k0 += 64) {
#pragma unroll
        for (int i = 0; i < 2; i++) {
            int c = tid + i * 256;
            int row = c >> 3, col = c & 7;
            int4 v = *reinterpret_cast<const int4*>(Ab + (long)(m0 + row) * Kd + k0 + col * 8);
            *reinterpret_cast<int4*>(&As[row * 72 + col * 8]) = v;
        }
#pragma unroll
        for (int i = 0; i < 4; i++) {
            int c = tid + i * 256;
            int row = c >> 3, col = c & 7;
            int4 v = *reinterpret_cast<const int4*>(Bb + (long)(n0 + row) * Kd + k0 + col * 8);
            *reinterpret_cast<int4*>(&Bs[row * 72 + col * 8]) = v;
        }
        __syncthreads();
#pragma unroll
        for (int kk = 0; kk < 64; kk += 32) {
            int klane = kk + 8 * (lane >> 4);
            half8 af[2], bfr[4];
#pragma unroll
            for (int fm = 0; fm < 2; fm++)
                af[fm] = *reinterpret_cast<const half8*>(&As[(wm * 32 + fm * 16 + (lane & 15)) * 72 + klane]);
#pragma unroll
            for (int fn = 0; fn < 4; fn++)
                bfr[fn] = *reinterpret_cast<const half8*>(&Bs[(wn * 64 + fn * 16 + (lane & 15)) * 72 + klane]);
#pragma unroll
            for (int fm = 0; fm < 2; fm++)
#pragma unroll
                for (int fn = 0; fn < 4; fn++)
                    acc[fm][fn] = __builtin_amdgcn_mfma_f32_16x16x32_f16(af[fm], bfr[fn], acc[fm][fn], 0, 0, 0);
        }
        __syncthreads();
    }

    long ob = (long)b * sOut;
#pragma unroll
    for (int fm = 0; fm < 2; fm++)
#pragma unroll
        for (int fn = 0; fn < 4; fn++)
#pragma unroll
            for (int r = 0; r < 4; r++) {
                int row = m0 + wm * 32 + fm * 16 + (lane >> 4) * 4 + r;
                int col = n0 + wn * 64 + fn * 16 + (lane & 15);
                Out[ob + (long)row * N + col] = (_Float16)acc[fm][fn][r];
            }
}

// ---------------- fused C + H + score kernel (both sides, XCD-swizzled) ----------------
// side C (P < 512):  sc_c[b,n0+j] = sum_k whx[k]*tanh(Wxd[k,n0+j] + sum_p Wpt[k,p]*C[p,n0+j])
// side P (P >= 512): sc_p[b,n0+j] = sum_k whp[k]*tanh(Wpt[k,n0+j] + sum_l Wxd[k,l]*C[n0+j,l])
// XCD swizzle (T1): x = P&7 selects XCD chunk; all tile-blocks of a batch share one XCD.
// Resident tile held as MFMA A-fragments in REGISTERS (no Rs in LDS) -> 38.1 KB LDS, 4 blocks/CU.
__global__ __launch_bounds__(256)
void k_score_fused(const _Float16* __restrict__ drug_h, const _Float16* __restrict__ tb_h,
                   const _Float16* __restrict__ Wxd_h, const _Float16* __restrict__ Wpt_h,
                   const float* __restrict__ whx, const float* __restrict__ whp,
                   float* __restrict__ sc_c, float* __restrict__ sc_p)
{
    __shared__ alignas(16) _Float16 Ss[64 * 136];   // streamed [64][128+8]
    __shared__ alignas(16) _Float16 Ws[64 * 72];    // W slice  [64k][64+8]
    __shared__ alignas(16) _Float16 Cts[64 * 72];   // C tile   [64res][64strm+8] (read-optimal stride)
    __shared__ float sred[8 * 64];
    __shared__ float wsh[64];

    int P = blockIdx.x;
    int tid = threadIdx.x;
    int lane = tid & 63;
    int wid = tid >> 6;
    int wm = wid & 1, wn = wid >> 1;

    int b, n0, nsteps, Ntot, sW;
    const _Float16 *R, *S, *W, *Add;
    const float* wv;
    float* out;
    if (P < 512) {
        int x = P & 7, j = P >> 3;            // x: XCD chunk; j in [0,64)
        b = x * 8 + (j >> 3);                  // batches [8x, 8x+8) on XCD x
        n0 = (j & 7) * 64;
        R = drug_h + (long)b * (LD * DD);
        S = tb_h   + (long)b * (LP * DD);
        W = Wpt_h  + (long)b * (KK * LP);  sW = LP;
        Add = Wxd_h + (long)b * (KK * LD); Ntot = LD;
        nsteps = LP / 64; wv = whx; out = sc_c + (long)b * LD;
    } else {
        int Q = P - 512;
        int x = Q & 7, j = Q >> 3;            // j in [0,128)
        b = x * 8 + (j >> 4);
        n0 = (j & 15) * 64;
        R = tb_h   + (long)b * (LP * DD);
        S = drug_h + (long)b * (LD * DD);
        W = Wxd_h  + (long)b * (KK * LD);  sW = LD;
        Add = Wpt_h + (long)b * (KK * LP); Ntot = LP;
        nsteps = LD / 64; wv = whp; out = sc_p + (long)b * LP;
    }

    // resident A-fragments in registers (loaded once; rows never change across steps)
    half8 af[2][4];
#pragma unroll
    for (int fm = 0; fm < 2; fm++)
#pragma unroll
        for (int kk = 0; kk < 4; kk++) {
            int row = n0 + wm * 32 + fm * 16 + (lane & 15);
            int col = kk * 32 + 8 * (lane >> 4);
            af[fm][kk] = *reinterpret_cast<const half8*>(R + (long)row * DD + col);
        }
    if (tid < 64) wsh[tid] = wv[tid];

    f32x4 acc2[2][2];
#pragma unroll
    for (int i = 0; i < 2; i++)
#pragma unroll
        for (int j = 0; j < 2; j++) acc2[i][j] = (f32x4)(0.0f);

    for (int s = 0; s < nsteps; s++) {
        __syncthreads();                  // (C) prev GEMM2 done; Ss/Ws free
        // stage stream tile [64][128]
#pragma unroll
        for (int i = 0; i < 4; i++) {
            int c = tid + i * 256;
            int row = c >> 4, col8 = (c & 15) * 8;
            int4 v = *reinterpret_cast<const int4*>(S + (long)(s * 64 + row) * DD + col8);
            *reinterpret_cast<int4*>(&Ss[row * 136 + col8]) = v;
        }
        // stage W slice [64][64]
#pragma unroll
        for (int i = 0; i < 2; i++) {
            int c = tid + i * 256;
            int row = c >> 3, col8 = (c & 7) * 8;
            int4 v = *reinterpret_cast<const int4*>(W + (long)row * sW + s * 64 + col8);
            *reinterpret_cast<int4*>(&Ws[row * 72 + col8]) = v;
        }
        __syncthreads();                  // (A) staging visible (covers wsh at s=0)

        // GEMM1: a1[res, strm] = sum_d af[res,d]*Ss[strm,d]
        f32x4 a1[2][2];
#pragma unroll
        for (int i = 0; i < 2; i++)
#pragma unroll
            for (int j = 0; j < 2; j++) a1[i][j] = (f32x4)(0.0f);
#pragma unroll
        for (int kk = 0; kk < 4; kk++) {
            int klane = kk * 32 + 8 * (lane >> 4);
            half8 bf[2];
#pragma unroll
            for (int fn = 0; fn < 2; fn++)
                bf[fn] = *reinterpret_cast<const half8*>(&Ss[(wn * 32 + fn * 16 + (lane & 15)) * 136 + klane]);
#pragma unroll
            for (int fm = 0; fm < 2; fm++)
#pragma unroll
                for (int fn = 0; fn < 2; fn++)
                    a1[fm][fn] = __builtin_amdgcn_mfma_f32_16x16x32_f16(af[fm][kk], bf[fn], a1[fm][fn], 0, 0, 0);
        }
        // tanh -> Cts [res][strm] (stride 72: b128 read path 2-way/free; b16 scatter 4-way)
#pragma unroll
        for (int fm = 0; fm < 2; fm++)
#pragma unroll
            for (int fn = 0; fn < 2; fn++)
#pragma unroll
                for (int r = 0; r < 4; r++) {
                    int res  = wm * 32 + fm * 16 + (lane >> 4) * 4 + r;
                    int strm = wn * 32 + fn * 16 + (lane & 15);
                    Cts[res * 72 + strm] = (_Float16)ftanh(a1[fm][fn][r]);
                }
        __syncthreads();                  // (B) Cts ready

        // GEMM2: acc2[k, res] += sum_strm Ws[k,strm]*Cts[res,strm]
#pragma unroll
        for (int kk = 0; kk < 2; kk++) {
            int klane = kk * 32 + 8 * (lane >> 4);
            half8 aw[2], bf[2];
#pragma unroll
            for (int fm = 0; fm < 2; fm++)
                aw[fm] = *reinterpret_cast<const half8*>(&Ws[(wm * 32 + fm * 16 + (lane & 15)) * 72 + klane]);
#pragma unroll
            for (int fn = 0; fn < 2; fn++)
                bf[fn] = *reinterpret_cast<const half8*>(&Cts[(wn * 32 + fn * 16 + (lane & 15)) * 72 + klane]);
#pragma unroll
            for (int fm = 0; fm < 2; fm++)
#pragma unroll
                for (int fn = 0; fn < 2; fn++)
                    acc2[fm][fn] = __builtin_amdgcn_mfma_f32_16x16x32_f16(aw[fm], bf[fn], acc2[fm][fn], 0, 0, 0);
        }
    }

    // epilogue: + Add, tanh, dot w, block reduce over k
    float ps[2] = {0.f, 0.f};
#pragma unroll
    for (int fm = 0; fm < 2; fm++)
#pragma unroll
        for (int fn = 0; fn < 2; fn++)
#pragma unroll
            for (int r = 0; r < 4; r++) {
                int k   = wm * 32 + fm * 16 + (lane >> 4) * 4 + r;
                int col = wn * 32 + fn * 16 + (lane & 15);
                float v = ftanh(acc2[fm][fn][r] + (float)Add[(long)k * Ntot + n0 + col]);
                ps[fn] += wsh[k] * v;
            }
#pragma unroll
    for (int fn = 0; fn < 2; fn++)
        sred[(wm * 4 + (lane >> 4)) * 64 + wn * 32 + fn * 16 + (lane & 15)] = ps[fn];
    __syncthreads();
    if (tid < 64) {
        float sacc = 0.f;
#pragma unroll
        for (int j = 0; j < 8; j++) sacc += sred[j * 64 + tid];
        out[n0 + tid] = sacc;
    }
}

// ---------------- softmax over scores ----------------
__device__ __forceinline__ float wred_max(float v) {
#pragma unroll
    for (int off = 32; off > 0; off >>= 1) v = fmaxf(v, __shfl_xor(v, off, 64));
    return v;
}
__device__ __forceinline__ float wred_sum(float v) {
#pragma unroll
    for (int off = 32; off > 0; off >>= 1) v += __shfl_xor(v, off, 64);
    return v;
}

__global__ __launch_bounds__(1024)
void k_soft(const float* __restrict__ scc, const float* __restrict__ scp,
            float* __restrict__ ac, float* __restrict__ ap)
{
    __shared__ float r16[16];
    int b = blockIdx.x, tid = threadIdx.x;
    int lane = tid & 63, wid = tid >> 6;

    float s = (tid < 512) ? scc[b * 512 + tid] : -3.4e38f;
    float m = wred_max(s);
    if (lane == 0) r16[wid] = m;
    __syncthreads();
    m = r16[0];
#pragma unroll
    for (int i = 1; i < 16; i++) m = fmaxf(m, r16[i]);
    float e = (tid < 512) ? __expf(s - m) : 0.f;
    __syncthreads();
    float t = wred_sum(e);
    if (lane == 0) r16[wid] = t;
    __syncthreads();
    float sum = 0.f;
#pragma unroll
    for (int i = 0; i < 16; i++) sum += r16[i];
    if (tid < 512) ac[b * 512 + tid] = e * __builtin_amdgcn_rcpf(sum);
    __syncthreads();

    float s2 = scp[b * 1024 + tid];
    float m2 = wred_max(s2);
    if (lane == 0) r16[wid] = m2;
    __syncthreads();
    m2 = r16[0];
#pragma unroll
    for (int i = 1; i < 16; i++) m2 = fmaxf(m2, r16[i]);
    float e2 = __expf(s2 - m2);
    __syncthreads();
    float t2 = wred_sum(e2);
    if (lane == 0) r16[wid] = t2;
    __syncthreads();
    float sum2 = 0.f;
#pragma unroll
    for (int i = 0; i < 16; i++) sum2 += r16[i];
    ap[b * 1024 + tid] = e2 * __builtin_amdgcn_rcpf(sum2);
}

// ---------------- weighted sums: out[b,d] = sum_l a[l] * X[b,l,d] ----------------
__global__ __launch_bounds__(512)
void k_wsum(const _Float16* __restrict__ drug_h, const _Float16* __restrict__ targ_h,
            const float* __restrict__ ac, const float* __restrict__ ap,
            float* __restrict__ out)
{
    __shared__ float ash[1024];
    __shared__ float red[32 * 128];
    int b = blockIdx.x, side = blockIdx.y;
    int L = side ? LP : LD;
    const _Float16* X = side ? targ_h : drug_h;
    const float* a = side ? ap : ac;
    float* ob = out + side * 8192 + b * 128;
    int tid = threadIdx.x;

    for (int i = tid; i < L; i += 512) ash[i] = a[(long)b * L + i];
    __syncthreads();

    int col8 = tid & 15, rg = tid >> 4;
    float accv[8];
#pragma unroll
    for (int j = 0; j < 8; j++) accv[j] = 0.f;
    const _Float16* Xb = X + (long)b * L * 128;
    for (int l = rg; l < L; l += 32) {
        half8 v = *reinterpret_cast<const half8*>(&Xb[l * 128 + col8 * 8]);
        float av = ash[l];
#pragma unroll
        for (int j = 0; j < 8; j++) accv[j] += av * (float)v[j];
    }
#pragma unroll
    for (int j = 0; j < 8; j++) red[rg * 128 + col8 * 8 + j] = accv[j];
    __syncthreads();
    if (tid < 128) {
        float s = 0.f;
#pragma unroll
        for (int g = 0; g < 32; g++) s += red[g * 128 + tid];
        ob[tid] = s;
    }
}

// ---------------- launch ----------------
extern "C" void kernel_launch(void* const* d_in, const int* in_sizes, int n_in,
                              void* d_out, int out_size, void* d_ws, size_t ws_size,
                              hipStream_t stream) {
    (void)in_sizes; (void)n_in; (void)out_size;
    const float* drug   = (const float*)d_in[0];
    const float* target = (const float*)d_in[1];
    const float* Wb     = (const float*)d_in[2];
    const float* Wx     = (const float*)d_in[3];
    const float* Wp     = (const float*)d_in[4];
    const float* whx    = (const float*)d_in[5];
    const float* whp    = (const float*)d_in[6];

    char* w = (char*)d_ws;
    size_t off = 0;
    auto takeb = [&](size_t bytes) {
        void* p = (void*)(w + off);
        off += (bytes + 255) & ~(size_t)255;
        return p;
    };
    _Float16* drug_h = (_Float16*)takeb((size_t)NB * LD * DD * 2);
    _Float16* targ_h = (_Float16*)takeb((size_t)NB * LP * DD * 2);
    _Float16* WbT_h  = (_Float16*)takeb(128 * 128 * 2);
    _Float16* Wx_h   = (_Float16*)takeb(64 * 128 * 2);
    _Float16* Wp_h   = (_Float16*)takeb(64 * 128 * 2);
    _Float16* tb_h   = (_Float16*)takeb((size_t)NB * LP * DD * 2);
    _Float16* Wxd_h  = (_Float16*)takeb((size_t)NB * KK * LD * 2);
    _Float16* Wpt_h  = (_Float16*)takeb((size_t)NB * KK * LP * 2);
    float*    sc_c   = (float*)takeb((size_t)NB * LD * 4);
    float*    sc_p   = (float*)takeb((size_t)NB * LP * 4);
    float*    a_c    = (float*)takeb((size_t)NB * LD * 4);
    float*    a_p    = (float*)takeb((size_t)NB * LP * 4);

    if (off > ws_size) {                 // workspace shortfall -> sentinel (absmax ~1000)
        k_sentinel<<<1, 64, 0, stream>>>((float*)d_out);
        return;
    }

    k_conv<<<1024, 256, 0, stream>>>(drug,   drug_h, NB * LD * DD);
    k_conv<<<1024, 256, 0, stream>>>(target, targ_h, NB * LP * DD);
    k_conv<<<16, 256, 0, stream>>>(Wx, Wx_h, 64 * 128);
    k_conv<<<16, 256, 0, stream>>>(Wp, Wp_h, 64 * 128);
    k_wbt<<<64, 256, 0, stream>>>(Wb, WbT_h);

    // tb[p,d] = sum_e target[p,e] * WbT[d,e]            M=LP  N=128 Kd=128
    k_gemm<<<dim3(NB * (LP / 64)), 256, 0, stream>>>(
        targ_h, (long)LP * DD, WbT_h, 0, tb_h, (long)LP * DD, 128, 128, LP / 64, 1);
    // Wxd[k,l] = sum_d Wx[k,d] * drug[l,d]              M=64  N=LD  Kd=128
    k_gemm<<<dim3(NB * (LD / 128)), 256, 0, stream>>>(
        Wx_h, 0, drug_h, (long)LD * DD, Wxd_h, (long)KK * LD, LD, 128, 1, LD / 128);
    // Wpt[k,p] = sum_e Wp[k,e] * target[p,e]            M=64  N=LP  Kd=128
    k_gemm<<<dim3(NB * (LP / 128)), 256, 0, stream>>>(
        Wp_h, 0, targ_h, (long)LP * DD, Wpt_h, (long)KK * LP, LP, 128, 1, LP / 128);

    // fused: C recomputed per side in-LDS; scores out directly
    k_score_fused<<<dim3(512 + 1024), 256, 0, stream>>>(
        drug_h, tb_h, Wxd_h, Wpt_h, whx, whp, sc_c, sc_p);

    k_soft<<<NB, 1024, 0, stream>>>(sc_c, sc_p, a_c, a_p);
    k_wsum<<<dim3(NB, 2), 512, 0, stream>>>(drug_h, targ_h, a_c, a_p, (float*)d_out);
}